// Round 13
// baseline (88.702 us; speedup 1.0000x reference)
//
#include <hip/hip_runtime.h>
#include <hip/hip_bf16.h>

typedef __bf16 bf16x8 __attribute__((ext_vector_type(8)));
typedef __bf16 bf16x4 __attribute__((ext_vector_type(4)));
typedef float  f32x4  __attribute__((ext_vector_type(4)));
typedef float  flt4v  __attribute__((ext_vector_type(4)));
typedef int    int4v  __attribute__((ext_vector_type(4)));

#define ALPHA 0.2f
#define LOG2E 1.44269504089f
// B=8, N=2048, D=128. Inputs: h,W,a f32; adj int32. Output f32.
//
// Wh stored MFMA-B-fragment-native: T[b][jt(32)][kk(2)][ct(8)][lane(64)][u(8)] bf16.
// element = Wh[j = jt*64+kk*32+(lane>>4)*8+u][col = ct*16+(lane&15)].

// spread 16 bits so bit m -> bit 4m
__device__ __forceinline__ unsigned long long spread4(unsigned long long x) {
    x &= 0xFFFFull;
    x = (x | (x << 24)) & 0x000000FF000000FFull;
    x = (x | (x << 12)) & 0x000F000F000F000Full;
    x = (x | (x << 6))  & 0x0303030303030303ull;
    x = (x | (x << 3))  & 0x1111111111111111ull;
    return x;
}

// Fused prep: blocks [0,2048) pack adj -> bitmask; blocks [2048,2304) Wh + scores.
__global__ __launch_bounds__(256) void gat_prep(
    const int*   __restrict__ adj,
    const float* __restrict__ h,
    const float* __restrict__ W,
    const float* __restrict__ a,
    unsigned long long* __restrict__ msk,    // [8*2048*32]
    __bf16* __restrict__ T,                  // [8][262144] bf16 tiled Wh
    float* __restrict__ ssrc,                // [8*2048] (x log2e)
    float* __restrict__ sdst)                // [8*2048] (x log2e)
{
    __shared__ __bf16 Wt[128][136];
    __shared__ float wvs[128], wvd[128];
    const int tid = threadIdx.x;

    if (blockIdx.x < 2048) {
        const int lane = tid & 63;
        const int wid  = (blockIdx.x * 256 + tid) >> 6;
        const int g0   = wid * 16;
        #pragma unroll 4
        for (int it = 0; it < 16; ++it) {
            const int g = g0 + it;
            int4v v = *reinterpret_cast<const int4v*>(adj + (size_t)g * 256 + lane * 4);
            unsigned long long b0 = __ballot(v[0] != 0);
            unsigned long long b1 = __ballot(v[1] != 0);
            unsigned long long b2 = __ballot(v[2] != 0);
            unsigned long long b3 = __ballot(v[3] != 0);
            if (lane < 4) {
                const int k = lane;
                unsigned long long w =  spread4(b0 >> (16 * k))
                                     | (spread4(b1 >> (16 * k)) << 1)
                                     | (spread4(b2 >> (16 * k)) << 2)
                                     | (spread4(b3 >> (16 * k)) << 3);
                msk[(size_t)g * 4 + k] = w;
            }
        }
        return;
    }

    const int bidw = blockIdx.x - 2048;
    if (tid < 128) {
        float s0 = 0.f, s1 = 0.f;
        const float* wr = W + tid * 128;
        #pragma unroll 4
        for (int e = 0; e < 128; ++e) {
            float w = wr[e];
            s0 += w * a[e];
            s1 += w * a[128 + e];
        }
        wvs[tid] = s0; wvd[tid] = s1;
    }
    #pragma unroll
    for (int it = 0; it < 8; ++it) {
        int o = (it * 256 + tid) * 8;
        flt4v v0 = *reinterpret_cast<const flt4v*>(W + o);
        flt4v v1 = *reinterpret_cast<const flt4v*>(W + o + 4);
        int d = o >> 7, e = o & 127;
        #pragma unroll
        for (int j = 0; j < 4; ++j) {
            Wt[e + j][d]     = (__bf16)v0[j];
            Wt[e + 4 + j][d] = (__bf16)v1[j];
        }
    }
    __syncthreads();
    const int wave = tid >> 6, lane = tid & 63;
    const int lr = lane & 15, lg = lane >> 4;
    const int row0 = bidw * 64 + wave * 16;
    f32x4 acc[8];
    #pragma unroll
    for (int ct = 0; ct < 8; ++ct) acc[ct] = (f32x4){0.f, 0.f, 0.f, 0.f};
    #pragma unroll
    for (int kk = 0; kk < 4; ++kk) {
        const float* hp = h + (size_t)(row0 + lr) * 128 + kk * 32 + lg * 8;
        flt4v h0 = *reinterpret_cast<const flt4v*>(hp);
        flt4v h1 = *reinterpret_cast<const flt4v*>(hp + 4);
        bf16x8 af;
        #pragma unroll
        for (int j = 0; j < 4; ++j) { af[j] = (__bf16)h0[j]; af[4 + j] = (__bf16)h1[j]; }
        #pragma unroll
        for (int ct = 0; ct < 8; ++ct) {
            bf16x8 bf_ = *reinterpret_cast<const bf16x8*>(&Wt[ct * 16 + lr][kk * 32 + lg * 8]);
            acc[ct] = __builtin_amdgcn_mfma_f32_16x16x32_bf16(af, bf_, acc[ct], 0, 0, 0);
        }
    }
    const int b  = row0 >> 11;
    const int n0 = row0 & 2047;
    __bf16* tb = T + (size_t)b * 262144;
    const int j0t = n0 + lg * 4;
    const int jt  = j0t >> 6;
    const int kk2 = (j0t >> 5) & 1;
    const int lgp = (j0t >> 3) & 3;
    const int u0  = j0t & 7;
    #pragma unroll
    for (int ct = 0; ct < 8; ++ct) {
        bf16x4 v;
        #pragma unroll
        for (int q = 0; q < 4; ++q) v[q] = (__bf16)acc[ct][q];
        *reinterpret_cast<bf16x4*>(tb + ((jt * 2 + kk2) * 8 + ct) * 512 + lgp * 128 + lr * 8 + u0) = v;
    }
    const float* hrow = h + (size_t)(row0 + lr) * 128 + lg * 32;
    float s0 = 0.f, s1 = 0.f;
    #pragma unroll
    for (int u = 0; u < 32; u += 4) {
        flt4v hv = *reinterpret_cast<const flt4v*>(hrow + u);
        #pragma unroll
        for (int q = 0; q < 4; ++q) {
            float x = hv[q];
            s0 += x * wvs[lg * 32 + u + q];
            s1 += x * wvd[lg * 32 + u + q];
        }
    }
    s0 += __shfl_xor(s0, 16, 64); s0 += __shfl_xor(s0, 32, 64);
    s1 += __shfl_xor(s1, 16, 64); s1 += __shfl_xor(s1, 32, 64);
    if (lg == 0) {
        ssrc[row0 + lr] = s0 * LOG2E;
        sdst[row0 + lr] = s1 * LOG2E;
    }
}

// Kernel C: fused masked-softmax attention + PV. Output f32.
// Grid: 512 blocks; bid&7 = batch (XCD pin), bid>>3 = 32-row tile (64/batch).
// Block: 256 thr = 4 waves = 4 j-slots. EACH WAVE computes BOTH 16-row groups:
// one B-frag load feeds 2 MFMAs (register B-sharing halves L1/L2 traffic).
// Denominator via MFMA against a ones-fragment (same bf16 P values as numerator).
__global__ __launch_bounds__(256) void gat_attn(
    const unsigned long long* __restrict__ msk, // [8*2048][32] u64 bitmask
    const __bf16* __restrict__ T,               // [8][262144] bf16 tiled Wh
    const float* __restrict__ ssrc,             // pre-scaled by log2e
    const float* __restrict__ sdst,             // pre-scaled by log2e
    float* __restrict__ out)                    // [8][2048][128] f32
{
    __shared__ float accsh[2][16][136];
    __shared__ float lsh[2][16];
    const int tid = threadIdx.x, slot = tid >> 6, lane = tid & 63;
    const int lr = lane & 15, lg = lane >> 4;
    const int b  = blockIdx.x & 7;
    const int i0 = (blockIdx.x >> 3) << 5;
    const int row0 = i0 + lr;                   // group-0 row
    const int row1 = i0 + 16 + lr;              // group-1 row
    const float si0 = ssrc[b * 2048 + row0];
    const float si1 = ssrc[b * 2048 + row1];
    const unsigned long long* mr0 = msk + (size_t)(b * 2048 + row0) * 32;
    const unsigned long long* mr1 = msk + (size_t)(b * 2048 + row1) * 32;
    const float* sd = sdst + b * 2048;
    const __bf16* tb = T + (size_t)b * 262144;

    bf16x8 ones;
    #pragma unroll
    for (int u = 0; u < 8; ++u) ones[u] = (__bf16)1.0f;

    f32x4 acc[2][8];
    f32x4 acc9[2];
    #pragma unroll
    for (int g = 0; g < 2; ++g) {
        acc9[g] = (f32x4){0.f, 0.f, 0.f, 0.f};
        #pragma unroll
        for (int ct = 0; ct < 8; ++ct) acc[g][ct] = (f32x4){0.f, 0.f, 0.f, 0.f};
    }

    #pragma unroll 2
    for (int t = 0; t < 8; ++t) {
        const int jt = slot + 4 * t;
        const int j0 = jt * 64;
        const unsigned long long mw0 = mr0[jt];
        const unsigned long long mw1 = mr1[jt];
        bf16x8 pf[2][2];                        // [kk][group]
        #pragma unroll
        for (int kk = 0; kk < 2; ++kk) {
            const int jb = j0 + kk * 32 + lg * 8;
            const unsigned int m80 = (unsigned int)(mw0 >> (kk * 32 + lg * 8)) & 0xffu;
            const unsigned int m81 = (unsigned int)(mw1 >> (kk * 32 + lg * 8)) & 0xffu;
            #pragma unroll
            for (int v = 0; v < 2; ++v) {
                flt4v sv = *reinterpret_cast<const flt4v*>(sd + jb + v * 4);
                #pragma unroll
                for (int u = 0; u < 4; ++u) {
                    float e0 = si0 + sv[u];
                    float e1 = si1 + sv[u];
                    e0 = fmaxf(e0, ALPHA * e0);
                    e1 = fmaxf(e1, ALPHA * e1);
                    float p0 = exp2f(e0);
                    float p1 = exp2f(e1);
                    p0 = (m80 & (1u << (v * 4 + u))) ? p0 : 0.f;
                    p1 = (m81 & (1u << (v * 4 + u))) ? p1 : 0.f;
                    pf[kk][0][v * 4 + u] = (__bf16)p0;
                    pf[kk][1][v * 4 + u] = (__bf16)p1;
                }
            }
        }
        #pragma unroll
        for (int kk = 0; kk < 2; ++kk) {
            const __bf16* tk = tb + ((jt * 2 + kk) * 8) * 512 + lane * 8;
            #pragma unroll
            for (int ct = 0; ct < 8; ++ct) {
                bf16x8 bf_ = *reinterpret_cast<const bf16x8*>(tk + ct * 512);
                acc[0][ct] = __builtin_amdgcn_mfma_f32_16x16x32_bf16(pf[kk][0], bf_, acc[0][ct], 0, 0, 0);
                acc[1][ct] = __builtin_amdgcn_mfma_f32_16x16x32_bf16(pf[kk][1], bf_, acc[1][ct], 0, 0, 0);
            }
            acc9[0] = __builtin_amdgcn_mfma_f32_16x16x32_bf16(pf[kk][0], ones, acc9[0], 0, 0, 0);
            acc9[1] = __builtin_amdgcn_mfma_f32_16x16x32_bf16(pf[kk][1], ones, acc9[1], 0, 0, 0);
        }
    }

    // merge 4 slot-waves sequentially (deterministic)
    #pragma unroll
    for (int s = 0; s < 4; ++s) {
        if (slot == s) {
            #pragma unroll
            for (int g = 0; g < 2; ++g) {
                if (s == 0) {
                    #pragma unroll
                    for (int ct = 0; ct < 8; ++ct)
                        #pragma unroll
                        for (int q = 0; q < 4; ++q)
                            accsh[g][lg * 4 + q][ct * 16 + lr] = acc[g][ct][q];
                    if (lr == 0) {
                        #pragma unroll
                        for (int q = 0; q < 4; ++q) lsh[g][lg * 4 + q] = acc9[g][q];
                    }
                } else {
                    #pragma unroll
                    for (int ct = 0; ct < 8; ++ct)
                        #pragma unroll
                        for (int q = 0; q < 4; ++q)
                            accsh[g][lg * 4 + q][ct * 16 + lr] += acc[g][ct][q];
                    if (lr == 0) {
                        #pragma unroll
                        for (int q = 0; q < 4; ++q) lsh[g][lg * 4 + q] += acc9[g][q];
                    }
                }
            }
        }
        __syncthreads();
    }

    // write out: 256 thr cover 32 rows x 128 cols (two 16-row halves)
    #pragma unroll
    for (int half = 0; half < 2; ++half) {
        const int rr = tid >> 4;                // 0..15
        const int c0 = (tid & 15) * 8;
        const int r  = half * 16 + rr;
        const float l = lsh[half][rr];
        float* ob = out + ((size_t)b * 2048 + i0 + r) * 128 + c0;
        flt4v o0, o1;
        #pragma unroll
        for (int u = 0; u < 4; ++u) {
            o0[u] = accsh[half][rr][c0 + u] / l;
            o1[u] = accsh[half][rr][c0 + 4 + u] / l;
        }
        *reinterpret_cast<flt4v*>(ob)     = o0;
        *reinterpret_cast<flt4v*>(ob + 4) = o1;
    }
}

extern "C" void kernel_launch(void* const* d_in, const int* in_sizes, int n_in,
                              void* d_out, int out_size, void* d_ws, size_t ws_size,
                              hipStream_t stream)
{
    const float* h = nullptr; const int* adj = nullptr;
    const float* W = nullptr; const float* a = nullptr;
    for (int i = 0; i < n_in; ++i) {
        switch (in_sizes[i]) {
            case 2097152:  h   = (const float*)d_in[i]; break;
            case 33554432: adj = (const int*)d_in[i];   break;
            case 16384:    W   = (const float*)d_in[i]; break;
            case 256:      a   = (const float*)d_in[i]; break;
        }
    }
    if (!h || !adj || !W || !a) {
        h   = (const float*)d_in[0];
        adj = (const int*)d_in[1];
        W   = (const float*)d_in[2];
        a   = (const float*)d_in[3];
    }

    __bf16* T = (__bf16*)d_ws;                                                // 4 MB
    unsigned long long* msk = (unsigned long long*)((char*)d_ws + (size_t)4*1024*1024); // 4 MB
    float* ssrc = (float*)((char*)d_ws + (size_t)8 * 1024 * 1024);            // 64 KB
    float* sdst = ssrc + 8 * 2048;                                            // 64 KB

    gat_prep<<<2304, 256, 0, stream>>>(adj, h, W, a, msk, T, ssrc, sdst);
    gat_attn<<<512, 256, 0, stream>>>(msk, T, ssrc, sdst, (float*)d_out);
}

// Round 14
// 84.234 us; speedup vs baseline: 1.0530x; 1.0530x over previous
//
#include <hip/hip_runtime.h>
#include <hip/hip_bf16.h>

typedef __bf16 bf16x8 __attribute__((ext_vector_type(8)));
typedef __bf16 bf16x4 __attribute__((ext_vector_type(4)));
typedef float  f32x4  __attribute__((ext_vector_type(4)));
typedef float  flt4v  __attribute__((ext_vector_type(4)));
typedef int    int4v  __attribute__((ext_vector_type(4)));

#define ALPHA 0.2f
#define LOG2E 1.44269504089f
// B=8, N=2048, D=128. Inputs: h,W,a f32; adj int32. Output f32.
// Wh stored MFMA-B-fragment-native: T[b][jt(32)][kk(2)][ct(8)][lane(64)][u(8)] bf16.

__device__ __forceinline__ unsigned long long spread4(unsigned long long x) {
    x &= 0xFFFFull;
    x = (x | (x << 24)) & 0x000000FF000000FFull;
    x = (x | (x << 12)) & 0x000F000F000F000Full;
    x = (x | (x << 6))  & 0x0303030303030303ull;
    x = (x | (x << 3))  & 0x1111111111111111ull;
    return x;
}

// Fused prep: blocks [0,2048) pack adj -> bitmask; blocks [2048,2304) Wh + scores.
__global__ __launch_bounds__(256) void gat_prep(
    const int*   __restrict__ adj,
    const float* __restrict__ h,
    const float* __restrict__ W,
    const float* __restrict__ a,
    unsigned long long* __restrict__ msk,    // [8*2048*32]
    __bf16* __restrict__ T,                  // [8][262144] bf16 tiled Wh
    float* __restrict__ ssrc,                // [8*2048] (x log2e)
    float* __restrict__ sdst)                // [8*2048] (x log2e)
{
    __shared__ __bf16 Wt[128][136];
    __shared__ float wvs[128], wvd[128];
    const int tid = threadIdx.x;

    if (blockIdx.x < 2048) {
        const int lane = tid & 63;
        const int wid  = (blockIdx.x * 256 + tid) >> 6;
        const int g0   = wid * 16;
        #pragma unroll 4
        for (int it = 0; it < 16; ++it) {
            const int g = g0 + it;
            int4v v = *reinterpret_cast<const int4v*>(adj + (size_t)g * 256 + lane * 4);
            unsigned long long b0 = __ballot(v[0] != 0);
            unsigned long long b1 = __ballot(v[1] != 0);
            unsigned long long b2 = __ballot(v[2] != 0);
            unsigned long long b3 = __ballot(v[3] != 0);
            if (lane < 4) {
                const int k = lane;
                unsigned long long w =  spread4(b0 >> (16 * k))
                                     | (spread4(b1 >> (16 * k)) << 1)
                                     | (spread4(b2 >> (16 * k)) << 2)
                                     | (spread4(b3 >> (16 * k)) << 3);
                msk[(size_t)g * 4 + k] = w;
            }
        }
        return;
    }

    const int bidw = blockIdx.x - 2048;
    if (tid < 128) {
        float s0 = 0.f, s1 = 0.f;
        const float* wr = W + tid * 128;
        #pragma unroll 4
        for (int e = 0; e < 128; ++e) {
            float w = wr[e];
            s0 += w * a[e];
            s1 += w * a[128 + e];
        }
        wvs[tid] = s0; wvd[tid] = s1;
    }
    #pragma unroll
    for (int it = 0; it < 8; ++it) {
        int o = (it * 256 + tid) * 8;
        flt4v v0 = *reinterpret_cast<const flt4v*>(W + o);
        flt4v v1 = *reinterpret_cast<const flt4v*>(W + o + 4);
        int d = o >> 7, e = o & 127;
        #pragma unroll
        for (int j = 0; j < 4; ++j) {
            Wt[e + j][d]     = (__bf16)v0[j];
            Wt[e + 4 + j][d] = (__bf16)v1[j];
        }
    }
    __syncthreads();
    const int wave = tid >> 6, lane = tid & 63;
    const int lr = lane & 15, lg = lane >> 4;
    const int row0 = bidw * 64 + wave * 16;
    f32x4 acc[8];
    #pragma unroll
    for (int ct = 0; ct < 8; ++ct) acc[ct] = (f32x4){0.f, 0.f, 0.f, 0.f};
    #pragma unroll
    for (int kk = 0; kk < 4; ++kk) {
        const float* hp = h + (size_t)(row0 + lr) * 128 + kk * 32 + lg * 8;
        flt4v h0 = *reinterpret_cast<const flt4v*>(hp);
        flt4v h1 = *reinterpret_cast<const flt4v*>(hp + 4);
        bf16x8 af;
        #pragma unroll
        for (int j = 0; j < 4; ++j) { af[j] = (__bf16)h0[j]; af[4 + j] = (__bf16)h1[j]; }
        #pragma unroll
        for (int ct = 0; ct < 8; ++ct) {
            bf16x8 bf_ = *reinterpret_cast<const bf16x8*>(&Wt[ct * 16 + lr][kk * 32 + lg * 8]);
            acc[ct] = __builtin_amdgcn_mfma_f32_16x16x32_bf16(af, bf_, acc[ct], 0, 0, 0);
        }
    }
    const int b  = row0 >> 11;
    const int n0 = row0 & 2047;
    __bf16* tb = T + (size_t)b * 262144;
    const int j0t = n0 + lg * 4;
    const int jt  = j0t >> 6;
    const int kk2 = (j0t >> 5) & 1;
    const int lgp = (j0t >> 3) & 3;
    const int u0  = j0t & 7;
    #pragma unroll
    for (int ct = 0; ct < 8; ++ct) {
        bf16x4 v;
        #pragma unroll
        for (int q = 0; q < 4; ++q) v[q] = (__bf16)acc[ct][q];
        *reinterpret_cast<bf16x4*>(tb + ((jt * 2 + kk2) * 8 + ct) * 512 + lgp * 128 + lr * 8 + u0) = v;
    }
    const float* hrow = h + (size_t)(row0 + lr) * 128 + lg * 32;
    float s0 = 0.f, s1 = 0.f;
    #pragma unroll
    for (int u = 0; u < 32; u += 4) {
        flt4v hv = *reinterpret_cast<const flt4v*>(hrow + u);
        #pragma unroll
        for (int q = 0; q < 4; ++q) {
            float x = hv[q];
            s0 += x * wvs[lg * 32 + u + q];
            s1 += x * wvd[lg * 32 + u + q];
        }
    }
    s0 += __shfl_xor(s0, 16, 64); s0 += __shfl_xor(s0, 32, 64);
    s1 += __shfl_xor(s1, 16, 64); s1 += __shfl_xor(s1, 32, 64);
    if (lg == 0) {
        ssrc[row0 + lr] = s0 * LOG2E;
        sdst[row0 + lr] = s1 * LOG2E;
    }
}

// Kernel C: fused masked-softmax attention + PV. Output f32.
// Grid: 512 blocks; bid&7 = batch (XCD pin), bid>>3 = 32-row tile.
// Block: 512 thr = 8 waves = 8 j-slots (jt = slot + 8t, t<4). Each wave computes
// BOTH 16-row groups: one B-frag load feeds 2 MFMAs. 2 blocks/CU x 8 waves = 16/CU.
// Scalar lpart denominators (saves 12 VGPR vs ones-MFMA; dodges 128-VGPR cliff).
__global__ __launch_bounds__(512) void gat_attn(
    const unsigned long long* __restrict__ msk, // [8*2048][32] u64 bitmask
    const __bf16* __restrict__ T,               // [8][262144] bf16 tiled Wh
    const float* __restrict__ ssrc,             // pre-scaled by log2e
    const float* __restrict__ sdst,             // pre-scaled by log2e
    float* __restrict__ out)                    // [8][2048][128] f32
{
    __shared__ float accsh[2][2][16][136];      // [half][group]
    __shared__ float lsh[2][2][16];
    const int tid = threadIdx.x, slot = tid >> 6, lane = tid & 63;
    const int lr = lane & 15, lg = lane >> 4;
    const int half = slot >> 2, s4 = slot & 3;
    const int b  = blockIdx.x & 7;
    const int i0 = (blockIdx.x >> 3) << 5;
    const int row0 = i0 + lr;
    const int row1 = i0 + 16 + lr;
    const float si0 = ssrc[b * 2048 + row0];
    const float si1 = ssrc[b * 2048 + row1];
    const unsigned long long* mr0 = msk + (size_t)(b * 2048 + row0) * 32;
    const unsigned long long* mr1 = msk + (size_t)(b * 2048 + row1) * 32;
    const float* sd = sdst + b * 2048;
    const __bf16* tb = T + (size_t)b * 262144;

    f32x4 acc[2][8];
    #pragma unroll
    for (int g = 0; g < 2; ++g)
        #pragma unroll
        for (int ct = 0; ct < 8; ++ct) acc[g][ct] = (f32x4){0.f, 0.f, 0.f, 0.f};
    float lp0 = 0.f, lp1 = 0.f;

    #pragma unroll 2
    for (int t = 0; t < 4; ++t) {
        const int jt = slot + 8 * t;
        const int j0 = jt * 64;
        const unsigned long long mw0 = mr0[jt];
        const unsigned long long mw1 = mr1[jt];
        bf16x8 pf[2][2];                        // [kk][group]
        #pragma unroll
        for (int kk = 0; kk < 2; ++kk) {
            const int jb = j0 + kk * 32 + lg * 8;
            const unsigned int m80 = (unsigned int)(mw0 >> (kk * 32 + lg * 8)) & 0xffu;
            const unsigned int m81 = (unsigned int)(mw1 >> (kk * 32 + lg * 8)) & 0xffu;
            #pragma unroll
            for (int v = 0; v < 2; ++v) {
                flt4v sv = *reinterpret_cast<const flt4v*>(sd + jb + v * 4);
                #pragma unroll
                for (int u = 0; u < 4; ++u) {
                    float e0 = si0 + sv[u];
                    float e1 = si1 + sv[u];
                    e0 = fmaxf(e0, ALPHA * e0);
                    e1 = fmaxf(e1, ALPHA * e1);
                    float p0 = exp2f(e0);
                    float p1 = exp2f(e1);
                    p0 = (m80 & (1u << (v * 4 + u))) ? p0 : 0.f;
                    p1 = (m81 & (1u << (v * 4 + u))) ? p1 : 0.f;
                    __bf16 pb0 = (__bf16)p0;
                    __bf16 pb1 = (__bf16)p1;
                    lp0 += (float)pb0;          // denom matches bf16 numerator
                    lp1 += (float)pb1;
                    pf[kk][0][v * 4 + u] = pb0;
                    pf[kk][1][v * 4 + u] = pb1;
                }
            }
        }
        #pragma unroll
        for (int kk = 0; kk < 2; ++kk) {
            const __bf16* tk = tb + ((jt * 2 + kk) * 8) * 512 + lane * 8;
            #pragma unroll
            for (int ct = 0; ct < 8; ++ct) {
                bf16x8 bf_ = *reinterpret_cast<const bf16x8*>(tk + ct * 512);
                acc[0][ct] = __builtin_amdgcn_mfma_f32_16x16x32_bf16(pf[kk][0], bf_, acc[0][ct], 0, 0, 0);
                acc[1][ct] = __builtin_amdgcn_mfma_f32_16x16x32_bf16(pf[kk][1], bf_, acc[1][ct], 0, 0, 0);
            }
        }
    }
    // reduce lpart over the 4 lg-groups (j-coverage within wave)
    lp0 += __shfl_xor(lp0, 16, 64); lp0 += __shfl_xor(lp0, 32, 64);
    lp1 += __shfl_xor(lp1, 16, 64); lp1 += __shfl_xor(lp1, 32, 64);

    // merge: halves (waves 0-3 | 4-7) in parallel, 4 sequential steps each
    #pragma unroll
    for (int s = 0; s < 4; ++s) {
        if (s4 == s) {
            #pragma unroll
            for (int g = 0; g < 2; ++g) {
                if (s == 0) {
                    #pragma unroll
                    for (int ct = 0; ct < 8; ++ct)
                        #pragma unroll
                        for (int q = 0; q < 4; ++q)
                            accsh[half][g][lg * 4 + q][ct * 16 + lr] = acc[g][ct][q];
                } else {
                    #pragma unroll
                    for (int ct = 0; ct < 8; ++ct)
                        #pragma unroll
                        for (int q = 0; q < 4; ++q)
                            accsh[half][g][lg * 4 + q][ct * 16 + lr] += acc[g][ct][q];
                }
            }
            if (lane < 16) {
                if (s == 0) { lsh[half][0][lr] = lp0; lsh[half][1][lr] = lp1; }
                else        { lsh[half][0][lr] += lp0; lsh[half][1][lr] += lp1; }
            }
        }
        __syncthreads();
    }

    // write out: 512 thr cover 32 rows x 128 cols
    const int r  = tid >> 4;                    // 0..31
    const int c0 = (tid & 15) * 8;
    const int rg = r >> 4, rr = r & 15;
    const float l = lsh[0][rg][rr] + lsh[1][rg][rr];
    float* ob = out + ((size_t)b * 2048 + i0 + r) * 128 + c0;
    flt4v o0, o1;
    #pragma unroll
    for (int u = 0; u < 4; ++u) {
        o0[u] = (accsh[0][rg][rr][c0 + u]     + accsh[1][rg][rr][c0 + u])     / l;
        o1[u] = (accsh[0][rg][rr][c0 + 4 + u] + accsh[1][rg][rr][c0 + 4 + u]) / l;
    }
    *reinterpret_cast<flt4v*>(ob)     = o0;
    *reinterpret_cast<flt4v*>(ob + 4) = o1;
}

extern "C" void kernel_launch(void* const* d_in, const int* in_sizes, int n_in,
                              void* d_out, int out_size, void* d_ws, size_t ws_size,
                              hipStream_t stream)
{
    const float* h = nullptr; const int* adj = nullptr;
    const float* W = nullptr; const float* a = nullptr;
    for (int i = 0; i < n_in; ++i) {
        switch (in_sizes[i]) {
            case 2097152:  h   = (const float*)d_in[i]; break;
            case 33554432: adj = (const int*)d_in[i];   break;
            case 16384:    W   = (const float*)d_in[i]; break;
            case 256:      a   = (const float*)d_in[i]; break;
        }
    }
    if (!h || !adj || !W || !a) {
        h   = (const float*)d_in[0];
        adj = (const int*)d_in[1];
        W   = (const float*)d_in[2];
        a   = (const float*)d_in[3];
    }

    __bf16* T = (__bf16*)d_ws;                                                // 4 MB
    unsigned long long* msk = (unsigned long long*)((char*)d_ws + (size_t)4*1024*1024); // 4 MB
    float* ssrc = (float*)((char*)d_ws + (size_t)8 * 1024 * 1024);            // 64 KB
    float* sdst = ssrc + 8 * 2048;                                            // 64 KB

    gat_prep<<<2304, 256, 0, stream>>>(adj, h, W, a, msk, T, ssrc, sdst);
    gat_attn<<<512, 512, 0, stream>>>(msk, T, ssrc, sdst, (float*)d_out);
}

// Round 15
// 68.785 us; speedup vs baseline: 1.2896x; 1.2246x over previous
//
#include <hip/hip_runtime.h>
#include <hip/hip_bf16.h>

typedef __bf16 bf16x8 __attribute__((ext_vector_type(8)));
typedef __bf16 bf16x4 __attribute__((ext_vector_type(4)));
typedef float  f32x4  __attribute__((ext_vector_type(4)));
typedef float  flt4v  __attribute__((ext_vector_type(4)));
typedef int    int4v  __attribute__((ext_vector_type(4)));

#define ALPHA 0.2f
#define LOG2E 1.44269504089f
// B=8, N=2048, D=128. Inputs: h,W,a f32; adj int32. Output f32.
// Wh stored MFMA-B-fragment-native: T[b][jt(32)][kk(2)][ct(8)][lane(64)][u(8)] bf16.
// msk[row][jt] u64, bit j-in-tile.

__device__ __forceinline__ unsigned long long spread4(unsigned long long x) {
    x &= 0xFFFFull;
    x = (x | (x << 24)) & 0x000000FF000000FFull;
    x = (x | (x << 12)) & 0x000F000F000F000Full;
    x = (x | (x << 6))  & 0x0303030303030303ull;
    x = (x | (x << 3))  & 0x1111111111111111ull;
    return x;
}

// Fused prep: blocks [0,2048) pack adj -> bitmask; blocks [2048,2304) Wh + scores.
__global__ __launch_bounds__(256) void gat_prep(
    const int*   __restrict__ adj,
    const float* __restrict__ h,
    const float* __restrict__ W,
    const float* __restrict__ a,
    unsigned long long* __restrict__ msk,    // [8*2048*32]
    __bf16* __restrict__ T,                  // [8][262144] bf16 tiled Wh
    float* __restrict__ ssrc,                // [8*2048] (x log2e)
    float* __restrict__ sdst)                // [8*2048] (x log2e)
{
    __shared__ __bf16 Wt[128][136];
    __shared__ float wvs[128], wvd[128];
    const int tid = threadIdx.x;

    if (blockIdx.x < 2048) {
        const int lane = tid & 63;
        const int wid  = (blockIdx.x * 256 + tid) >> 6;
        const int g0   = wid * 16;
        #pragma unroll 4
        for (int it = 0; it < 16; ++it) {
            const int g = g0 + it;
            int4v v = *reinterpret_cast<const int4v*>(adj + (size_t)g * 256 + lane * 4);
            unsigned long long b0 = __ballot(v[0] != 0);
            unsigned long long b1 = __ballot(v[1] != 0);
            unsigned long long b2 = __ballot(v[2] != 0);
            unsigned long long b3 = __ballot(v[3] != 0);
            if (lane < 4) {
                const int k = lane;
                unsigned long long w =  spread4(b0 >> (16 * k))
                                     | (spread4(b1 >> (16 * k)) << 1)
                                     | (spread4(b2 >> (16 * k)) << 2)
                                     | (spread4(b3 >> (16 * k)) << 3);
                msk[(size_t)g * 4 + k] = w;
            }
        }
        return;
    }

    const int bidw = blockIdx.x - 2048;
    if (tid < 128) {
        float s0 = 0.f, s1 = 0.f;
        const float* wr = W + tid * 128;
        #pragma unroll 4
        for (int e = 0; e < 128; ++e) {
            float w = wr[e];
            s0 += w * a[e];
            s1 += w * a[128 + e];
        }
        wvs[tid] = s0; wvd[tid] = s1;
    }
    #pragma unroll
    for (int it = 0; it < 8; ++it) {
        int o = (it * 256 + tid) * 8;
        flt4v v0 = *reinterpret_cast<const flt4v*>(W + o);
        flt4v v1 = *reinterpret_cast<const flt4v*>(W + o + 4);
        int d = o >> 7, e = o & 127;
        #pragma unroll
        for (int j = 0; j < 4; ++j) {
            Wt[e + j][d]     = (__bf16)v0[j];
            Wt[e + 4 + j][d] = (__bf16)v1[j];
        }
    }
    __syncthreads();
    const int wave = tid >> 6, lane = tid & 63;
    const int lr = lane & 15, lg = lane >> 4;
    const int row0 = bidw * 64 + wave * 16;
    f32x4 acc[8];
    #pragma unroll
    for (int ct = 0; ct < 8; ++ct) acc[ct] = (f32x4){0.f, 0.f, 0.f, 0.f};
    #pragma unroll
    for (int kk = 0; kk < 4; ++kk) {
        const float* hp = h + (size_t)(row0 + lr) * 128 + kk * 32 + lg * 8;
        flt4v h0 = *reinterpret_cast<const flt4v*>(hp);
        flt4v h1 = *reinterpret_cast<const flt4v*>(hp + 4);
        bf16x8 af;
        #pragma unroll
        for (int j = 0; j < 4; ++j) { af[j] = (__bf16)h0[j]; af[4 + j] = (__bf16)h1[j]; }
        #pragma unroll
        for (int ct = 0; ct < 8; ++ct) {
            bf16x8 bf_ = *reinterpret_cast<const bf16x8*>(&Wt[ct * 16 + lr][kk * 32 + lg * 8]);
            acc[ct] = __builtin_amdgcn_mfma_f32_16x16x32_bf16(af, bf_, acc[ct], 0, 0, 0);
        }
    }
    const int b  = row0 >> 11;
    const int n0 = row0 & 2047;
    __bf16* tb = T + (size_t)b * 262144;
    const int j0t = n0 + lg * 4;
    const int jt  = j0t >> 6;
    const int kk2 = (j0t >> 5) & 1;
    const int lgp = (j0t >> 3) & 3;
    const int u0  = j0t & 7;
    #pragma unroll
    for (int ct = 0; ct < 8; ++ct) {
        bf16x4 v;
        #pragma unroll
        for (int q = 0; q < 4; ++q) v[q] = (__bf16)acc[ct][q];
        *reinterpret_cast<bf16x4*>(tb + ((jt * 2 + kk2) * 8 + ct) * 512 + lgp * 128 + lr * 8 + u0) = v;
    }
    const float* hrow = h + (size_t)(row0 + lr) * 128 + lg * 32;
    float s0 = 0.f, s1 = 0.f;
    #pragma unroll
    for (int u = 0; u < 32; u += 4) {
        flt4v hv = *reinterpret_cast<const flt4v*>(hrow + u);
        #pragma unroll
        for (int q = 0; q < 4; ++q) {
            float x = hv[q];
            s0 += x * wvs[lg * 32 + u + q];
            s1 += x * wvd[lg * 32 + u + q];
        }
    }
    s0 += __shfl_xor(s0, 16, 64); s0 += __shfl_xor(s0, 32, 64);
    s1 += __shfl_xor(s1, 16, 64); s1 += __shfl_xor(s1, 32, 64);
    if (lg == 0) {
        ssrc[row0 + lr] = s0 * LOG2E;
        sdst[row0 + lr] = s1 * LOG2E;
    }
}

// Kernel C: fused masked-softmax attention + PV, P staged through LDS.
// Grid: 512 blocks (bid&7 = batch/XCD pin, bid>>3 = 32-row tile). Block: 512 thr = 8 waves.
// Wave w: P-role (g1=w>>2, kk1=(w>>1)&1, uh=w&1) computes a disjoint P slice ->
// LDS in A-frag-native layout. MFMA-role (kkR=w>>2, cp=w&3): owns kk-half x col-pair;
// no B-frag is loaded twice in a block. Epilogue merges kk-halves via LDS.
__global__ __launch_bounds__(512) void gat_attn(
    const unsigned long long* __restrict__ msk, // [8*2048][32] u64
    const __bf16* __restrict__ T,               // [8][262144] bf16 tiled Wh
    const float* __restrict__ ssrc,             // x log2e
    const float* __restrict__ sdst,             // x log2e
    float* __restrict__ out)                    // [8][2048][128] f32
{
    __shared__ __bf16 Pl[8][512];               // [t2*4+g*2+kk][lane*8 + u] (8 KB)
    __shared__ float  lsum[2][4][16];
    __shared__ f32x4  mbuf[4][2][2][64];        // kk=1 partial accs (16 KB)

    const int tid = threadIdx.x, w = tid >> 6, l = tid & 63;
    const int lr = l & 15, lg = l >> 4;
    const int g1 = w >> 2, kk1 = (w >> 1) & 1, uh = w & 1;  // P-role
    const int kkR = w >> 2, cp = w & 3;                     // MFMA-role
    const int b  = blockIdx.x & 7;
    const int i0 = (blockIdx.x >> 3) << 5;

    const int rowm = i0 + g1 * 16 + lr;         // P-role row
    const float si = ssrc[b * 2048 + rowm];
    const unsigned long long* mrow = msk + (size_t)(b * 2048 + rowm) * 32;
    const float* sd = sdst + b * 2048;
    const __bf16* tb = T + (size_t)b * 262144;
    const int jb = kk1 * 32 + lg * 8 + uh * 4;  // P-role j offset within tile

    f32x4 acc[2][2];
    #pragma unroll
    for (int g = 0; g < 2; ++g)
        #pragma unroll
        for (int c2 = 0; c2 < 2; ++c2) acc[g][c2] = (f32x4){0.f, 0.f, 0.f, 0.f};
    float lrow = 0.f;

    #pragma unroll 1
    for (int iv = 0; iv < 16; ++iv) {
        const int jt0 = iv * 2;
        const unsigned long long m0 = mrow[jt0];
        const unsigned long long m1 = mrow[jt0 + 1];
        // ---- phase 1: P slices -> LDS (A-frag-native) ----
        #pragma unroll
        for (int t2 = 0; t2 < 2; ++t2) {
            const unsigned long long mw = t2 ? m1 : m0;
            flt4v sv = *reinterpret_cast<const flt4v*>(sd + (jt0 + t2) * 64 + jb);
            const unsigned int m4 = (unsigned int)(mw >> jb) & 0xFu;
            bf16x4 pw;
            #pragma unroll
            for (int u = 0; u < 4; ++u) {
                float e = si + sv[u];
                e = fmaxf(e, ALPHA * e);         // leaky_relu (log2-domain, c>0 commutes)
                float p = exp2f(e);
                p = (m4 & (1u << u)) ? p : 0.f;
                __bf16 pb = (__bf16)p;
                lrow += (float)pb;               // denom matches bf16 numerator
                pw[u] = pb;
            }
            *reinterpret_cast<bf16x4*>(&Pl[t2 * 4 + g1 * 2 + kk1][l * 8 + uh * 4]) = pw;
        }
        __syncthreads();
        // ---- phase 2: MFMA on (kkR, cp) slab ----
        #pragma unroll
        for (int t2 = 0; t2 < 2; ++t2) {
            const int jt = jt0 + t2;
            const __bf16* tk = tb + (size_t)(((jt * 2 + kkR) * 8) + cp * 2) * 512 + l * 8;
            bf16x8 b0 = *reinterpret_cast<const bf16x8*>(tk);
            bf16x8 b1 = *reinterpret_cast<const bf16x8*>(tk + 512);
            #pragma unroll
            for (int g = 0; g < 2; ++g) {
                bf16x8 af = *reinterpret_cast<const bf16x8*>(&Pl[t2 * 4 + g * 2 + kkR][l * 8]);
                acc[g][0] = __builtin_amdgcn_mfma_f32_16x16x32_bf16(af, b0, acc[g][0], 0, 0, 0);
                acc[g][1] = __builtin_amdgcn_mfma_f32_16x16x32_bf16(af, b1, acc[g][1], 0, 0, 0);
            }
        }
        __syncthreads();
    }

    // denominators: reduce over lg groups; one slot per (g1, kk1*2+uh)
    lrow += __shfl_xor(lrow, 16, 64);
    lrow += __shfl_xor(lrow, 32, 64);
    if (l < 16) lsum[g1][kk1 * 2 + uh][l] = lrow;
    // kk=1 waves publish their partial accumulators
    if (kkR == 1) {
        #pragma unroll
        for (int g = 0; g < 2; ++g)
            #pragma unroll
            for (int c2 = 0; c2 < 2; ++c2)
                mbuf[cp][g][c2][l] = acc[g][c2];
    }
    __syncthreads();
    // kk=0 waves merge + write output (each element written exactly once)
    if (kkR == 0) {
        #pragma unroll
        for (int g = 0; g < 2; ++g) {
            float den[4];
            #pragma unroll
            for (int q = 0; q < 4; ++q) {
                const int rl = lg * 4 + q;
                den[q] = lsum[g][0][rl] + lsum[g][1][rl] + lsum[g][2][rl] + lsum[g][3][rl];
            }
            #pragma unroll
            for (int c2 = 0; c2 < 2; ++c2) {
                f32x4 av = acc[g][c2];
                f32x4 mv = mbuf[cp][g][c2][l];
                const int col = (cp * 2 + c2) * 16 + lr;
                #pragma unroll
                for (int q = 0; q < 4; ++q) {
                    const int row = i0 + g * 16 + lg * 4 + q;
                    out[((size_t)b * 2048 + row) * 128 + col] = (av[q] + mv[q]) / den[q];
                }
            }
        }
    }
}

extern "C" void kernel_launch(void* const* d_in, const int* in_sizes, int n_in,
                              void* d_out, int out_size, void* d_ws, size_t ws_size,
                              hipStream_t stream)
{
    const float* h = nullptr; const int* adj = nullptr;
    const float* W = nullptr; const float* a = nullptr;
    for (int i = 0; i < n_in; ++i) {
        switch (in_sizes[i]) {
            case 2097152:  h   = (const float*)d_in[i]; break;
            case 33554432: adj = (const int*)d_in[i];   break;
            case 16384:    W   = (const float*)d_in[i]; break;
            case 256:      a   = (const float*)d_in[i]; break;
        }
    }
    if (!h || !adj || !W || !a) {
        h   = (const float*)d_in[0];
        adj = (const int*)d_in[1];
        W   = (const float*)d_in[2];
        a   = (const float*)d_in[3];
    }

    __bf16* T = (__bf16*)d_ws;                                                // 4 MB
    unsigned long long* msk = (unsigned long long*)((char*)d_ws + (size_t)4*1024*1024); // 4 MB
    float* ssrc = (float*)((char*)d_ws + (size_t)8 * 1024 * 1024);            // 64 KB
    float* sdst = ssrc + 8 * 2048;                                            // 64 KB

    gat_prep<<<2304, 256, 0, stream>>>(adj, h, W, a, msk, T, ssrc, sdst);
    gat_attn<<<512, 512, 0, stream>>>(msk, T, ssrc, sdst, (float*)d_out);
}

// Round 16
// 67.567 us; speedup vs baseline: 1.3128x; 1.0180x over previous
//
#include <hip/hip_runtime.h>
#include <hip/hip_bf16.h>

typedef __bf16 bf16x8 __attribute__((ext_vector_type(8)));
typedef __bf16 bf16x4 __attribute__((ext_vector_type(4)));
typedef float  f32x4  __attribute__((ext_vector_type(4)));
typedef float  flt4v  __attribute__((ext_vector_type(4)));
typedef int    int4v  __attribute__((ext_vector_type(4)));

#define ALPHA 0.2f
#define LOG2E 1.44269504089f
// B=8, N=2048, D=128. Inputs: h,W,a f32; adj int32. Output f32.
// Wh stored MFMA-B-fragment-native: T[b][jt(32)][kk(2)][ct(8)][lane(64)][u(8)] bf16.

__device__ __forceinline__ unsigned long long spread4(unsigned long long x) {
    x &= 0xFFFFull;
    x = (x | (x << 24)) & 0x000000FF000000FFull;
    x = (x | (x << 12)) & 0x000F000F000F000Full;
    x = (x | (x << 6))  & 0x0303030303030303ull;
    x = (x | (x << 3))  & 0x1111111111111111ull;
    return x;
}

// Fused prep: blocks [0,2048) pack adj -> bitmask; blocks [2048,2304) Wh + scores.
__global__ __launch_bounds__(256) void gat_prep(
    const int*   __restrict__ adj,
    const float* __restrict__ h,
    const float* __restrict__ W,
    const float* __restrict__ a,
    unsigned long long* __restrict__ msk,    // [8*2048*32]
    __bf16* __restrict__ T,                  // [8][262144] bf16 tiled Wh
    float* __restrict__ ssrc,                // [8*2048] (x log2e)
    float* __restrict__ sdst)                // [8*2048] (x log2e)
{
    __shared__ __bf16 Wt[128][136];
    __shared__ float wvs[128], wvd[128];
    const int tid = threadIdx.x;

    if (blockIdx.x < 2048) {
        const int lane = tid & 63;
        const int wid  = (blockIdx.x * 256 + tid) >> 6;
        const int g0   = wid * 16;
        #pragma unroll 4
        for (int it = 0; it < 16; ++it) {
            const int g = g0 + it;
            int4v v = *reinterpret_cast<const int4v*>(adj + (size_t)g * 256 + lane * 4);
            unsigned long long b0 = __ballot(v[0] != 0);
            unsigned long long b1 = __ballot(v[1] != 0);
            unsigned long long b2 = __ballot(v[2] != 0);
            unsigned long long b3 = __ballot(v[3] != 0);
            if (lane < 4) {
                const int k = lane;
                unsigned long long w =  spread4(b0 >> (16 * k))
                                     | (spread4(b1 >> (16 * k)) << 1)
                                     | (spread4(b2 >> (16 * k)) << 2)
                                     | (spread4(b3 >> (16 * k)) << 3);
                msk[(size_t)g * 4 + k] = w;
            }
        }
        return;
    }

    const int bidw = blockIdx.x - 2048;
    if (tid < 128) {
        float s0 = 0.f, s1 = 0.f;
        const float* wr = W + tid * 128;
        #pragma unroll 4
        for (int e = 0; e < 128; ++e) {
            float w = wr[e];
            s0 += w * a[e];
            s1 += w * a[128 + e];
        }
        wvs[tid] = s0; wvd[tid] = s1;
    }
    #pragma unroll
    for (int it = 0; it < 8; ++it) {
        int o = (it * 256 + tid) * 8;
        flt4v v0 = *reinterpret_cast<const flt4v*>(W + o);
        flt4v v1 = *reinterpret_cast<const flt4v*>(W + o + 4);
        int d = o >> 7, e = o & 127;
        #pragma unroll
        for (int j = 0; j < 4; ++j) {
            Wt[e + j][d]     = (__bf16)v0[j];
            Wt[e + 4 + j][d] = (__bf16)v1[j];
        }
    }
    __syncthreads();
    const int wave = tid >> 6, lane = tid & 63;
    const int lr = lane & 15, lg = lane >> 4;
    const int row0 = bidw * 64 + wave * 16;
    f32x4 acc[8];
    #pragma unroll
    for (int ct = 0; ct < 8; ++ct) acc[ct] = (f32x4){0.f, 0.f, 0.f, 0.f};
    #pragma unroll
    for (int kk = 0; kk < 4; ++kk) {
        const float* hp = h + (size_t)(row0 + lr) * 128 + kk * 32 + lg * 8;
        flt4v h0 = *reinterpret_cast<const flt4v*>(hp);
        flt4v h1 = *reinterpret_cast<const flt4v*>(hp + 4);
        bf16x8 af;
        #pragma unroll
        for (int j = 0; j < 4; ++j) { af[j] = (__bf16)h0[j]; af[4 + j] = (__bf16)h1[j]; }
        #pragma unroll
        for (int ct = 0; ct < 8; ++ct) {
            bf16x8 bf_ = *reinterpret_cast<const bf16x8*>(&Wt[ct * 16 + lr][kk * 32 + lg * 8]);
            acc[ct] = __builtin_amdgcn_mfma_f32_16x16x32_bf16(af, bf_, acc[ct], 0, 0, 0);
        }
    }
    const int b  = row0 >> 11;
    const int n0 = row0 & 2047;
    __bf16* tb = T + (size_t)b * 262144;
    const int j0t = n0 + lg * 4;
    const int jt  = j0t >> 6;
    const int kk2 = (j0t >> 5) & 1;
    const int lgp = (j0t >> 3) & 3;
    const int u0  = j0t & 7;
    #pragma unroll
    for (int ct = 0; ct < 8; ++ct) {
        bf16x4 v;
        #pragma unroll
        for (int q = 0; q < 4; ++q) v[q] = (__bf16)acc[ct][q];
        *reinterpret_cast<bf16x4*>(tb + ((jt * 2 + kk2) * 8 + ct) * 512 + lgp * 128 + lr * 8 + u0) = v;
    }
    const float* hrow = h + (size_t)(row0 + lr) * 128 + lg * 32;
    float s0 = 0.f, s1 = 0.f;
    #pragma unroll
    for (int u = 0; u < 32; u += 4) {
        flt4v hv = *reinterpret_cast<const flt4v*>(hrow + u);
        #pragma unroll
        for (int q = 0; q < 4; ++q) {
            float x = hv[q];
            s0 += x * wvs[lg * 32 + u + q];
            s1 += x * wvd[lg * 32 + u + q];
        }
    }
    s0 += __shfl_xor(s0, 16, 64); s0 += __shfl_xor(s0, 32, 64);
    s1 += __shfl_xor(s1, 16, 64); s1 += __shfl_xor(s1, 32, 64);
    if (lg == 0) {
        ssrc[row0 + lr] = s0 * LOG2E;
        sdst[row0 + lr] = s1 * LOG2E;
    }
}

// Kernel C: fused masked-softmax attention + PV, P staged through LDS,
// SOFTWARE-PIPELINED: double-buffered Pl, ONE barrier per interval (17 total).
// Interval iv: [next-P input loads | B-frag loads | A-frag ds_reads | 8 MFMAs |
// exp + ds_write P(iv+1) -> other buffer | barrier].
__global__ __launch_bounds__(512) void gat_attn(
    const unsigned long long* __restrict__ msk, // [8*2048][32] u64
    const __bf16* __restrict__ T,               // [8][262144] bf16 tiled Wh
    const float* __restrict__ ssrc,             // x log2e
    const float* __restrict__ sdst,             // x log2e
    float* __restrict__ out)                    // [8][2048][128] f32
{
    __shared__ __bf16 Pl[2][8][512];            // double-buffered A-frag P (16 KB)
    __shared__ float  lsum[2][4][16];
    __shared__ f32x4  mbuf[4][2][2][64];        // kk=1 partial accs (16 KB)

    const int tid = threadIdx.x, w = tid >> 6, l = tid & 63;
    const int lr = l & 15, lg = l >> 4;
    const int g1 = w >> 2, kk1 = (w >> 1) & 1, uh = w & 1;  // P-role
    const int kkR = w >> 2, cp = w & 3;                     // MFMA-role
    const int b  = blockIdx.x & 7;
    const int i0 = (blockIdx.x >> 3) << 5;

    const int rowm = i0 + g1 * 16 + lr;
    const float si = ssrc[b * 2048 + rowm];
    const unsigned long long* mrow = msk + (size_t)(b * 2048 + rowm) * 32;
    const float* sd = sdst + b * 2048;
    const __bf16* tb = T + (size_t)b * 262144;
    const int jb = kk1 * 32 + lg * 8 + uh * 4;

    f32x4 acc[2][2];
    #pragma unroll
    for (int g = 0; g < 2; ++g)
        #pragma unroll
        for (int c2 = 0; c2 < 2; ++c2) acc[g][c2] = (f32x4){0.f, 0.f, 0.f, 0.f};
    float lrow = 0.f;

    // ---- prologue: P(interval 0) -> Pl[0] ----
    {
        const unsigned long long m0 = mrow[0];
        const unsigned long long m1 = mrow[1];
        #pragma unroll
        for (int t2 = 0; t2 < 2; ++t2) {
            const unsigned long long mw = t2 ? m1 : m0;
            flt4v sv = *reinterpret_cast<const flt4v*>(sd + t2 * 64 + jb);
            const unsigned int m4 = (unsigned int)(mw >> jb) & 0xFu;
            bf16x4 pw;
            #pragma unroll
            for (int u = 0; u < 4; ++u) {
                float e = si + sv[u];
                e = fmaxf(e, ALPHA * e);
                float p = exp2f(e);
                p = (m4 & (1u << u)) ? p : 0.f;
                __bf16 pb = (__bf16)p;
                lrow += (float)pb;
                pw[u] = pb;
            }
            *reinterpret_cast<bf16x4*>(&Pl[0][t2 * 4 + g1 * 2 + kk1][l * 8 + uh * 4]) = pw;
        }
    }
    __syncthreads();

    // ---- pipelined main loop: one barrier per interval ----
    #pragma unroll 2
    for (int iv = 0; iv < 16; ++iv) {
        const int cur = iv & 1, nxt = cur ^ 1;
        const int jt0 = iv * 2;
        // (1) next-interval P input loads (issued early, consumed late)
        unsigned long long mn0 = 0, mn1 = 0;
        flt4v svn0, svn1;
        if (iv < 15) {
            mn0 = mrow[jt0 + 2];
            mn1 = mrow[jt0 + 3];
            svn0 = *reinterpret_cast<const flt4v*>(sd + (jt0 + 2) * 64 + jb);
            svn1 = *reinterpret_cast<const flt4v*>(sd + (jt0 + 3) * 64 + jb);
        }
        // (2) current B-frag global loads
        const __bf16* tk0 = tb + (size_t)(((jt0 * 2 + kkR) * 8) + cp * 2) * 512 + l * 8;
        const __bf16* tk1 = tb + (size_t)((((jt0 + 1) * 2 + kkR) * 8) + cp * 2) * 512 + l * 8;
        bf16x8 b00 = *reinterpret_cast<const bf16x8*>(tk0);
        bf16x8 b01 = *reinterpret_cast<const bf16x8*>(tk0 + 512);
        bf16x8 b10 = *reinterpret_cast<const bf16x8*>(tk1);
        bf16x8 b11 = *reinterpret_cast<const bf16x8*>(tk1 + 512);
        // (3) current A-frag LDS reads
        bf16x8 a00 = *reinterpret_cast<const bf16x8*>(&Pl[cur][0 * 4 + 0 * 2 + kkR][l * 8]);
        bf16x8 a01 = *reinterpret_cast<const bf16x8*>(&Pl[cur][0 * 4 + 1 * 2 + kkR][l * 8]);
        bf16x8 a10 = *reinterpret_cast<const bf16x8*>(&Pl[cur][1 * 4 + 0 * 2 + kkR][l * 8]);
        bf16x8 a11 = *reinterpret_cast<const bf16x8*>(&Pl[cur][1 * 4 + 1 * 2 + kkR][l * 8]);
        // (4) MFMAs
        acc[0][0] = __builtin_amdgcn_mfma_f32_16x16x32_bf16(a00, b00, acc[0][0], 0, 0, 0);
        acc[0][1] = __builtin_amdgcn_mfma_f32_16x16x32_bf16(a00, b01, acc[0][1], 0, 0, 0);
        acc[1][0] = __builtin_amdgcn_mfma_f32_16x16x32_bf16(a01, b00, acc[1][0], 0, 0, 0);
        acc[1][1] = __builtin_amdgcn_mfma_f32_16x16x32_bf16(a01, b01, acc[1][1], 0, 0, 0);
        acc[0][0] = __builtin_amdgcn_mfma_f32_16x16x32_bf16(a10, b10, acc[0][0], 0, 0, 0);
        acc[0][1] = __builtin_amdgcn_mfma_f32_16x16x32_bf16(a10, b11, acc[0][1], 0, 0, 0);
        acc[1][0] = __builtin_amdgcn_mfma_f32_16x16x32_bf16(a11, b10, acc[1][0], 0, 0, 0);
        acc[1][1] = __builtin_amdgcn_mfma_f32_16x16x32_bf16(a11, b11, acc[1][1], 0, 0, 0);
        // (5) exp + ds_write next-P into other buffer
        if (iv < 15) {
            #pragma unroll
            for (int t2 = 0; t2 < 2; ++t2) {
                const unsigned long long mw = t2 ? mn1 : mn0;
                const flt4v sv = t2 ? svn1 : svn0;
                const unsigned int m4 = (unsigned int)(mw >> jb) & 0xFu;
                bf16x4 pw;
                #pragma unroll
                for (int u = 0; u < 4; ++u) {
                    float e = si + sv[u];
                    e = fmaxf(e, ALPHA * e);
                    float p = exp2f(e);
                    p = (m4 & (1u << u)) ? p : 0.f;
                    __bf16 pb = (__bf16)p;
                    lrow += (float)pb;
                    pw[u] = pb;
                }
                *reinterpret_cast<bf16x4*>(&Pl[nxt][t2 * 4 + g1 * 2 + kk1][l * 8 + uh * 4]) = pw;
            }
        }
        // (6) single barrier
        __syncthreads();
    }

    // denominators + kk-half merge (unchanged)
    lrow += __shfl_xor(lrow, 16, 64);
    lrow += __shfl_xor(lrow, 32, 64);
    if (l < 16) lsum[g1][kk1 * 2 + uh][l] = lrow;
    if (kkR == 1) {
        #pragma unroll
        for (int g = 0; g < 2; ++g)
            #pragma unroll
            for (int c2 = 0; c2 < 2; ++c2)
                mbuf[cp][g][c2][l] = acc[g][c2];
    }
    __syncthreads();
    if (kkR == 0) {
        #pragma unroll
        for (int g = 0; g < 2; ++g) {
            float den[4];
            #pragma unroll
            for (int q = 0; q < 4; ++q) {
                const int rl = lg * 4 + q;
                den[q] = lsum[g][0][rl] + lsum[g][1][rl] + lsum[g][2][rl] + lsum[g][3][rl];
            }
            #pragma unroll
            for (int c2 = 0; c2 < 2; ++c2) {
                f32x4 av = acc[g][c2];
                f32x4 mv = mbuf[cp][g][c2][l];
                const int col = (cp * 2 + c2) * 16 + lr;
                #pragma unroll
                for (int q = 0; q < 4; ++q) {
                    const int row = i0 + g * 16 + lg * 4 + q;
                    out[((size_t)b * 2048 + row) * 128 + col] = (av[q] + mv[q]) / den[q];
                }
            }
        }
    }
}

extern "C" void kernel_launch(void* const* d_in, const int* in_sizes, int n_in,
                              void* d_out, int out_size, void* d_ws, size_t ws_size,
                              hipStream_t stream)
{
    const float* h = nullptr; const int* adj = nullptr;
    const float* W = nullptr; const float* a = nullptr;
    for (int i = 0; i < n_in; ++i) {
        switch (in_sizes[i]) {
            case 2097152:  h   = (const float*)d_in[i]; break;
            case 33554432: adj = (const int*)d_in[i];   break;
            case 16384:    W   = (const float*)d_in[i]; break;
            case 256:      a   = (const float*)d_in[i]; break;
        }
    }
    if (!h || !adj || !W || !a) {
        h   = (const float*)d_in[0];
        adj = (const int*)d_in[1];
        W   = (const float*)d_in[2];
        a   = (const float*)d_in[3];
    }

    __bf16* T = (__bf16*)d_ws;                                                // 4 MB
    unsigned long long* msk = (unsigned long long*)((char*)d_ws + (size_t)4*1024*1024); // 4 MB
    float* ssrc = (float*)((char*)d_ws + (size_t)8 * 1024 * 1024);            // 64 KB
    float* sdst = ssrc + 8 * 2048;                                            // 64 KB

    gat_prep<<<2304, 256, 0, stream>>>(adj, h, W, a, msk, T, ssrc, sdst);
    gat_attn<<<512, 512, 0, stream>>>(msk, T, ssrc, sdst, (float*)d_out);
}

// Round 17
// 46.660 us; speedup vs baseline: 1.9010x; 1.4481x over previous
//
#include <hip/hip_runtime.h>
#include <hip/hip_bf16.h>

typedef __bf16 bf16x8 __attribute__((ext_vector_type(8)));
typedef __bf16 bf16x4 __attribute__((ext_vector_type(4)));
typedef float  f32x4  __attribute__((ext_vector_type(4)));
typedef float  flt4v  __attribute__((ext_vector_type(4)));
typedef int    int4v  __attribute__((ext_vector_type(4)));

#define ALPHA 0.2f
#define LOG2E 1.44269504089f
// B=8, N=2048, D=128. Inputs: h,W,a f32; adj int32. Output f32.
// Wh stored MFMA-B-fragment-native: T[b][jt(32)][kk(2)][ct(8)][lane(64)][u(8)] bf16.

// Kernel A: Wh + scores only (pack kernel deleted — attn streams adj directly).
__global__ __launch_bounds__(256) void gat_wh(
    const float* __restrict__ h,
    const float* __restrict__ W,
    const float* __restrict__ a,
    __bf16* __restrict__ T,                  // [8][262144] bf16 tiled Wh
    float* __restrict__ ssrc,                // [8*2048] (x log2e)
    float* __restrict__ sdst)                // [8*2048] (x log2e)
{
    __shared__ __bf16 Wt[128][136];
    __shared__ float wvs[128], wvd[128];
    const int tid = threadIdx.x;
    if (tid < 128) {
        float s0 = 0.f, s1 = 0.f;
        const float* wr = W + tid * 128;
        #pragma unroll 4
        for (int e = 0; e < 128; ++e) {
            float w = wr[e];
            s0 += w * a[e];
            s1 += w * a[128 + e];
        }
        wvs[tid] = s0; wvd[tid] = s1;
    }
    #pragma unroll
    for (int it = 0; it < 8; ++it) {
        int o = (it * 256 + tid) * 8;
        flt4v v0 = *reinterpret_cast<const flt4v*>(W + o);
        flt4v v1 = *reinterpret_cast<const flt4v*>(W + o + 4);
        int d = o >> 7, e = o & 127;
        #pragma unroll
        for (int j = 0; j < 4; ++j) {
            Wt[e + j][d]     = (__bf16)v0[j];
            Wt[e + 4 + j][d] = (__bf16)v1[j];
        }
    }
    __syncthreads();
    const int wave = tid >> 6, lane = tid & 63;
    const int lr = lane & 15, lg = lane >> 4;
    const int row0 = blockIdx.x * 64 + wave * 16;
    f32x4 acc[8];
    #pragma unroll
    for (int ct = 0; ct < 8; ++ct) acc[ct] = (f32x4){0.f, 0.f, 0.f, 0.f};
    #pragma unroll
    for (int kk = 0; kk < 4; ++kk) {
        const float* hp = h + (size_t)(row0 + lr) * 128 + kk * 32 + lg * 8;
        flt4v h0 = *reinterpret_cast<const flt4v*>(hp);
        flt4v h1 = *reinterpret_cast<const flt4v*>(hp + 4);
        bf16x8 af;
        #pragma unroll
        for (int j = 0; j < 4; ++j) { af[j] = (__bf16)h0[j]; af[4 + j] = (__bf16)h1[j]; }
        #pragma unroll
        for (int ct = 0; ct < 8; ++ct) {
            bf16x8 bf_ = *reinterpret_cast<const bf16x8*>(&Wt[ct * 16 + lr][kk * 32 + lg * 8]);
            acc[ct] = __builtin_amdgcn_mfma_f32_16x16x32_bf16(af, bf_, acc[ct], 0, 0, 0);
        }
    }
    const int b  = row0 >> 11;
    const int n0 = row0 & 2047;
    __bf16* tb = T + (size_t)b * 262144;
    const int j0t = n0 + lg * 4;
    const int jt  = j0t >> 6;
    const int kk2 = (j0t >> 5) & 1;
    const int lgp = (j0t >> 3) & 3;
    const int u0  = j0t & 7;
    #pragma unroll
    for (int ct = 0; ct < 8; ++ct) {
        bf16x4 v;
        #pragma unroll
        for (int q = 0; q < 4; ++q) v[q] = (__bf16)acc[ct][q];
        *reinterpret_cast<bf16x4*>(tb + ((jt * 2 + kk2) * 8 + ct) * 512 + lgp * 128 + lr * 8 + u0) = v;
    }
    const float* hrow = h + (size_t)(row0 + lr) * 128 + lg * 32;
    float s0 = 0.f, s1 = 0.f;
    #pragma unroll
    for (int u = 0; u < 32; u += 4) {
        flt4v hv = *reinterpret_cast<const flt4v*>(hrow + u);
        #pragma unroll
        for (int q = 0; q < 4; ++q) {
            float x = hv[q];
            s0 += x * wvs[lg * 32 + u + q];
            s1 += x * wvd[lg * 32 + u + q];
        }
    }
    s0 += __shfl_xor(s0, 16, 64); s0 += __shfl_xor(s0, 32, 64);
    s1 += __shfl_xor(s1, 16, 64); s1 += __shfl_xor(s1, 32, 64);
    if (lg == 0) {
        ssrc[row0 + lr] = s0 * LOG2E;
        sdst[row0 + lr] = s1 * LOG2E;
    }
}

// Kernel C: fused masked-softmax attention + PV, P staged through LDS, pipelined.
// Reads adj DIRECTLY (no pre-pack): P-role wave w owns rows 4w..4w+3; lane l:
// row = i0+4w+(l>>4), j-chunk = (l&15)*8 of the 128-j interval -> 16 consecutive
// lanes read 512B contiguous adj/sdst (coalesced). P written as one bf16x8 into
// A-frag-native LDS (j=(l&15)*8+u => t2=(l&15)>>3, kk=((l&15)>>2)&1, lgp=(l&15)&3).
// MFMA-role (kkR=w>>2, cp=w&3) unchanged: kk-split, no B-frag loaded twice.
__global__ __launch_bounds__(512) void gat_attn(
    const int* __restrict__ adj,                // [8][2048][2048]
    const __bf16* __restrict__ T,               // [8][262144] bf16 tiled Wh
    const float* __restrict__ ssrc,             // x log2e
    const float* __restrict__ sdst,             // x log2e
    float* __restrict__ out)                    // [8][2048][128] f32
{
    __shared__ __bf16 Pl[2][8][512];            // double-buffered A-frag P (16 KB)
    __shared__ float  lsumf[32];
    __shared__ f32x4  mbuf[4][2][2][64];        // kk=1 partial accs (16 KB)

    const int tid = threadIdx.x, w = tid >> 6, l = tid & 63;
    const int lr = l & 15, lg = l >> 4;
    const int kkR = w >> 2, cp = w & 3;         // MFMA-role
    const int b  = blockIdx.x & 7;
    const int i0 = (blockIdx.x >> 3) << 5;

    // P-role geometry
    const int prow = 4 * w + (l >> 4);          // row within 32-tile
    const int row  = i0 + prow;
    const int jc   = (l & 15) * 8;              // j-chunk within 128-j interval
    const int pt2  = (l & 15) >> 3;
    const int pkk  = ((l & 15) >> 2) & 1;
    const int plgp = (l & 15) & 3;
    const int pbuf = pt2 * 4 + (w >> 2) * 2 + pkk;
    const int pslot = (prow & 15) + plgp * 16;
    const float si = ssrc[b * 2048 + row];
    const int* arow = adj + ((size_t)b * 2048 + row) * 2048;
    const float* sd = sdst + b * 2048;
    const __bf16* tb = T + (size_t)b * 262144;

    f32x4 acc[2][2];
    #pragma unroll
    for (int g = 0; g < 2; ++g)
        #pragma unroll
        for (int c2 = 0; c2 < 2; ++c2) acc[g][c2] = (f32x4){0.f, 0.f, 0.f, 0.f};
    float lrow = 0.f;

    // ---- prologue: P(interval 0) -> Pl[0] ----
    {
        int4v a0 = *reinterpret_cast<const int4v*>(arow + jc);
        int4v a1 = *reinterpret_cast<const int4v*>(arow + jc + 4);
        flt4v s0 = *reinterpret_cast<const flt4v*>(sd + jc);
        flt4v s1 = *reinterpret_cast<const flt4v*>(sd + jc + 4);
        bf16x8 pw;
        #pragma unroll
        for (int u = 0; u < 4; ++u) {
            float e0 = si + s0[u], e1 = si + s1[u];
            e0 = fmaxf(e0, ALPHA * e0); e1 = fmaxf(e1, ALPHA * e1);
            float p0 = exp2f(e0), p1 = exp2f(e1);
            p0 = (a0[u] != 0) ? p0 : 0.f;
            p1 = (a1[u] != 0) ? p1 : 0.f;
            __bf16 pb0 = (__bf16)p0, pb1 = (__bf16)p1;
            lrow += (float)pb0 + (float)pb1;
            pw[u] = pb0; pw[4 + u] = pb1;
        }
        *reinterpret_cast<bf16x8*>(&Pl[0][pbuf][pslot * 8]) = pw;
    }
    __syncthreads();

    // ---- pipelined main loop: one barrier per interval ----
    #pragma unroll 2
    for (int iv = 0; iv < 16; ++iv) {
        const int cur = iv & 1, nxt = cur ^ 1;
        const int jt0 = iv * 2;
        // (1) next-interval adj + sdst loads (issued early)
        int4v an0 = {0,0,0,0}, an1 = {0,0,0,0};
        flt4v sn0, sn1;
        if (iv < 15) {
            const int off = (iv + 1) * 128 + jc;
            an0 = *reinterpret_cast<const int4v*>(arow + off);
            an1 = *reinterpret_cast<const int4v*>(arow + off + 4);
            sn0 = *reinterpret_cast<const flt4v*>(sd + off);
            sn1 = *reinterpret_cast<const flt4v*>(sd + off + 4);
        }
        // (2) current B-frag global loads
        const __bf16* tk0 = tb + (size_t)(((jt0 * 2 + kkR) * 8) + cp * 2) * 512 + l * 8;
        const __bf16* tk1 = tb + (size_t)((((jt0 + 1) * 2 + kkR) * 8) + cp * 2) * 512 + l * 8;
        bf16x8 b00 = *reinterpret_cast<const bf16x8*>(tk0);
        bf16x8 b01 = *reinterpret_cast<const bf16x8*>(tk0 + 512);
        bf16x8 b10 = *reinterpret_cast<const bf16x8*>(tk1);
        bf16x8 b11 = *reinterpret_cast<const bf16x8*>(tk1 + 512);
        // (3) current A-frag LDS reads
        bf16x8 a00 = *reinterpret_cast<const bf16x8*>(&Pl[cur][0 + 0 + kkR][l * 8]);
        bf16x8 a01 = *reinterpret_cast<const bf16x8*>(&Pl[cur][0 + 2 + kkR][l * 8]);
        bf16x8 a10 = *reinterpret_cast<const bf16x8*>(&Pl[cur][4 + 0 + kkR][l * 8]);
        bf16x8 a11 = *reinterpret_cast<const bf16x8*>(&Pl[cur][4 + 2 + kkR][l * 8]);
        // (4) MFMAs
        acc[0][0] = __builtin_amdgcn_mfma_f32_16x16x32_bf16(a00, b00, acc[0][0], 0, 0, 0);
        acc[0][1] = __builtin_amdgcn_mfma_f32_16x16x32_bf16(a00, b01, acc[0][1], 0, 0, 0);
        acc[1][0] = __builtin_amdgcn_mfma_f32_16x16x32_bf16(a01, b00, acc[1][0], 0, 0, 0);
        acc[1][1] = __builtin_amdgcn_mfma_f32_16x16x32_bf16(a01, b01, acc[1][1], 0, 0, 0);
        acc[0][0] = __builtin_amdgcn_mfma_f32_16x16x32_bf16(a10, b10, acc[0][0], 0, 0, 0);
        acc[0][1] = __builtin_amdgcn_mfma_f32_16x16x32_bf16(a10, b11, acc[0][1], 0, 0, 0);
        acc[1][0] = __builtin_amdgcn_mfma_f32_16x16x32_bf16(a11, b10, acc[1][0], 0, 0, 0);
        acc[1][1] = __builtin_amdgcn_mfma_f32_16x16x32_bf16(a11, b11, acc[1][1], 0, 0, 0);
        // (5) exp + ds_write next-P into other buffer
        if (iv < 15) {
            bf16x8 pw;
            #pragma unroll
            for (int u = 0; u < 4; ++u) {
                float e0 = si + sn0[u], e1 = si + sn1[u];
                e0 = fmaxf(e0, ALPHA * e0); e1 = fmaxf(e1, ALPHA * e1);
                float p0 = exp2f(e0), p1 = exp2f(e1);
                p0 = (an0[u] != 0) ? p0 : 0.f;
                p1 = (an1[u] != 0) ? p1 : 0.f;
                __bf16 pb0 = (__bf16)p0, pb1 = (__bf16)p1;
                lrow += (float)pb0 + (float)pb1;
                pw[u] = pb0; pw[4 + u] = pb1;
            }
            *reinterpret_cast<bf16x8*>(&Pl[nxt][pbuf][pslot * 8]) = pw;
        }
        // (6) single barrier
        __syncthreads();
    }

    // denominators: each row owned by one 16-lane group
    lrow += __shfl_xor(lrow, 1, 64);
    lrow += __shfl_xor(lrow, 2, 64);
    lrow += __shfl_xor(lrow, 4, 64);
    lrow += __shfl_xor(lrow, 8, 64);
    if ((l & 15) == 0) lsumf[prow] = lrow;
    // kk=1 waves publish their partial accumulators
    if (kkR == 1) {
        #pragma unroll
        for (int g = 0; g < 2; ++g)
            #pragma unroll
            for (int c2 = 0; c2 < 2; ++c2)
                mbuf[cp][g][c2][l] = acc[g][c2];
    }
    __syncthreads();
    // kk=0 waves merge + write output
    if (kkR == 0) {
        #pragma unroll
        for (int g = 0; g < 2; ++g) {
            float den[4];
            #pragma unroll
            for (int q = 0; q < 4; ++q) den[q] = lsumf[g * 16 + lg * 4 + q];
            #pragma unroll
            for (int c2 = 0; c2 < 2; ++c2) {
                f32x4 av = acc[g][c2];
                f32x4 mv = mbuf[cp][g][c2][l];
                const int col = (cp * 2 + c2) * 16 + lr;
                #pragma unroll
                for (int q = 0; q < 4; ++q) {
                    const int orow = i0 + g * 16 + lg * 4 + q;
                    out[((size_t)b * 2048 + orow) * 128 + col] = (av[q] + mv[q]) / den[q];
                }
            }
        }
    }
}

extern "C" void kernel_launch(void* const* d_in, const int* in_sizes, int n_in,
                              void* d_out, int out_size, void* d_ws, size_t ws_size,
                              hipStream_t stream)
{
    const float* h = nullptr; const int* adj = nullptr;
    const float* W = nullptr; const float* a = nullptr;
    for (int i = 0; i < n_in; ++i) {
        switch (in_sizes[i]) {
            case 2097152:  h   = (const float*)d_in[i]; break;
            case 33554432: adj = (const int*)d_in[i];   break;
            case 16384:    W   = (const float*)d_in[i]; break;
            case 256:      a   = (const float*)d_in[i]; break;
        }
    }
    if (!h || !adj || !W || !a) {
        h   = (const float*)d_in[0];
        adj = (const int*)d_in[1];
        W   = (const float*)d_in[2];
        a   = (const float*)d_in[3];
    }

    __bf16* T = (__bf16*)d_ws;                                        // 4 MB
    float* ssrc = (float*)((char*)d_ws + (size_t)4 * 1024 * 1024);    // 64 KB
    float* sdst = ssrc + 8 * 2048;                                    // 64 KB

    gat_wh<<<256, 256, 0, stream>>>(h, W, a, T, ssrc, sdst);
    gat_attn<<<512, 512, 0, stream>>>(adj, T, ssrc, sdst, (float*)d_out);
}